// Round 5
// baseline (1100.129 us; speedup 1.0000x reference)
//
#include <hip/hip_runtime.h>
#include <hip/hip_bf16.h>
#include <cstdint>

// ---------------------------------------------------------------------------
// GRU-D: B=256, T=512, D=128, H=256.
// x-path (LOCF, input decay, mask proj, all GEMMs vs inputs) is h-independent
// and precomputed in parallel; the recurrent scan keeps R in registers spread
// across 8 waves, wave-local columns, state in registers (R3 structure).
// R4: z-GEMV moved from phase A to phase B, REUSING the phase-A hd_bf A-operand
// fragments (afr[8], 32 VGPRs) across bar1. Post-bar1 the wave issues 16
// z-MFMAs immediately from registers (621 cyc/SIMD pipe work) while the u_bf
// ds_reads (~120 cyc latency) fly — the A->B transition gap disappears under
// matrix-pipe work. Phase A = r-GEMV only; its epilogue is 5 ops. sigmoid(z)
// overlaps the hh-MFMAs. Numerically identical to R3.
// (R4 resubmit — previous round was an infra failure, kernel never ran.)
// ---------------------------------------------------------------------------

#define Bsz 256
#define Tsz 512
#define Dsz 128
#define Hsz 256
#define BT  (Bsz * Tsz)          // 131072
#define N3H 768                  // 3*H

typedef __attribute__((ext_vector_type(8))) short   short8;
typedef __attribute__((ext_vector_type(8))) __bf16  bf16x8;
typedef __attribute__((ext_vector_type(4))) float   f32x4;

__device__ __forceinline__ unsigned short f2bf(float f) {
    union { float f; unsigned u; } v; v.f = f;
    unsigned r = v.u + 0x7fffu + ((v.u >> 16) & 1u);   // RNE
    return (unsigned short)(r >> 16);
}
__device__ __forceinline__ float b2f(unsigned short u) {
    union { unsigned u; float f; } v; v.u = ((unsigned)u) << 16;
    return v.f;
}
__device__ __forceinline__ bf16x8 ld_frag(const unsigned short* p) {
    short8 v = *(const short8*)p;
    return __builtin_bit_cast(bf16x8, v);
}

// LDS-only barrier: drains lgkmcnt (ds_write visibility) but NOT vmcnt, so
// global stores (h output) and the t+2 prefetch loads remain in flight.
// All cross-wave traffic at these sync points is through LDS.
__device__ __forceinline__ void barrier_lds() {
    asm volatile("s_waitcnt lgkmcnt(0)\n\ts_barrier" ::: "memory");
}

// ---------------------------------------------------------------------------
// K0: transpose+convert weights to bf16, N-major.
// ---------------------------------------------------------------------------
__global__ void k_pack(const float* __restrict__ kern, const float* __restrict__ maskk,
                       const float* __restrict__ rk,   const float* __restrict__ hdk,
                       unsigned short* __restrict__ KM_T, unsigned short* __restrict__ R_T,
                       unsigned short* __restrict__ W_T) {
    int i = blockIdx.x * 256 + threadIdx.x;
    if (i < N3H * 256) {
        int n = i >> 8, k = i & 255;
        float v = (k < 128) ? kern[k * N3H + n] : maskk[(k - 128) * N3H + n];
        KM_T[i] = f2bf(v);
        R_T[i]  = f2bf(rk[k * N3H + n]);
    } else {
        int j = i - N3H * 256;
        if (j < 256 * 128) {
            int n = j >> 7, k = j & 127;
            W_T[j] = f2bf(hdk[k * 256 + n]);
        }
    }
}

// ---------------------------------------------------------------------------
// K1: LOCF scan, one thread per (b,d).
// ---------------------------------------------------------------------------
__global__ __launch_bounds__(256) void k_locf(
        const float* __restrict__ x, const int* __restrict__ m,
        const float* __restrict__ s, const float* __restrict__ wdi,
        const float* __restrict__ bdi,
        unsigned short* __restrict__ X2, unsigned short* __restrict__ Dt) {
    int gid = blockIdx.x * blockDim.x + threadIdx.x;   // 32768
    int b = gid >> 7, d = gid & 127;
    float w  = wdi[d], bi = bdi[d];
    float x_keep = 0.f, s_prev = 0.f;
    const float* xb  = x + (size_t)b * Tsz * Dsz + d;
    const int*   mb_ = m + (size_t)b * Tsz * Dsz + d;
    const float* sb  = s + (size_t)b * Tsz;
    unsigned short* X2b = X2 + (size_t)b * Tsz * 256 + d;
    unsigned short* Dtb = Dt + (size_t)b * Tsz * 128 + d;
    for (int t0 = 0; t0 < Tsz; t0 += 4) {
        float xv[4], sv[4]; int mv[4];
#pragma unroll
        for (int u = 0; u < 4; u++) {
            xv[u] = xb[(size_t)(t0 + u) * Dsz];
            mv[u] = mb_[(size_t)(t0 + u) * Dsz];
            sv[u] = sb[t0 + u];
        }
#pragma unroll
        for (int u = 0; u < 4; u++) {
            int t = t0 + u;
            float dt  = sv[u] - s_prev;
            float gdi = __expf(-fmaxf(dt * w + bi, 0.f));
            bool  mbt = mv[u] > 0;
            if (mbt) x_keep = xv[u];
            float xe = mbt ? xv[u] : gdi * x_keep;
            if (mbt) s_prev = sv[u];
            X2b[(size_t)t * 256]       = f2bf(xe);
            X2b[(size_t)t * 256 + 128] = f2bf((float)mv[u]);
            Dtb[(size_t)t * 128]       = f2bf(dt);
        }
    }
}

// ---------------------------------------------------------------------------
// K2: bf16 MFMA GEMM, 128x128 tile, BK=32, 4 waves (2x2 of 64x64).
// MODE 0: C = A@B + bias ; MODE 1: C = exp(-relu(A@B + bias)). C bf16.
// ---------------------------------------------------------------------------
template <int MODE, int K, int N>
__global__ __launch_bounds__(256) void k_gemm(
        const unsigned short* __restrict__ A, const unsigned short* __restrict__ Bt,
        const float* __restrict__ bias, unsigned short* __restrict__ C) {
    __shared__ unsigned short As[128][40];
    __shared__ unsigned short Bs[128][40];
    int m0 = blockIdx.x * 128, n0 = blockIdx.y * 128;
    int tid = threadIdx.x, lane = tid & 63, w = tid >> 6;
    int wm = w & 1, wn = w >> 1;
    int r15 = lane & 15, q = lane >> 4;
    int arow = tid >> 2, akg = tid & 3;
    f32x4 acc[4][4];
#pragma unroll
    for (int i = 0; i < 4; i++)
#pragma unroll
        for (int j = 0; j < 4; j++) acc[i][j] = f32x4{0.f, 0.f, 0.f, 0.f};

    for (int kk = 0; kk < K; kk += 32) {
        short8 av0 = *(const short8*)(A  + (size_t)(m0 + arow)      * K + kk + akg * 8);
        short8 av1 = *(const short8*)(A  + (size_t)(m0 + arow + 64) * K + kk + akg * 8);
        short8 bv0 = *(const short8*)(Bt + (size_t)(n0 + arow)      * K + kk + akg * 8);
        short8 bv1 = *(const short8*)(Bt + (size_t)(n0 + arow + 64) * K + kk + akg * 8);
        *(short8*)&As[arow][akg * 8]      = av0;
        *(short8*)&As[arow + 64][akg * 8] = av1;
        *(short8*)&Bs[arow][akg * 8]      = bv0;
        *(short8*)&Bs[arow + 64][akg * 8] = bv1;
        __syncthreads();
        bf16x8 af[4], bf[4];
#pragma unroll
        for (int i = 0; i < 4; i++) af[i] = ld_frag(&As[wm * 64 + i * 16 + r15][q * 8]);
#pragma unroll
        for (int j = 0; j < 4; j++) bf[j] = ld_frag(&Bs[wn * 64 + j * 16 + r15][q * 8]);
#pragma unroll
        for (int i = 0; i < 4; i++)
#pragma unroll
            for (int j = 0; j < 4; j++)
                acc[i][j] = __builtin_amdgcn_mfma_f32_16x16x32_bf16(af[i], bf[j], acc[i][j], 0, 0, 0);
        __syncthreads();
    }
#pragma unroll
    for (int i = 0; i < 4; i++)
#pragma unroll
        for (int j = 0; j < 4; j++) {
            int col = n0 + wn * 64 + j * 16 + r15;
            float bs = bias[col];
#pragma unroll
            for (int rg = 0; rg < 4; rg++) {
                int row = m0 + wm * 64 + i * 16 + q * 4 + rg;
                float v = acc[i][j][rg] + bs;
                if (MODE == 1) v = __expf(-fmaxf(v, 0.f));
                C[(size_t)row * N + col] = f2bf(v);
            }
        }
}

// ---------------------------------------------------------------------------
// K3: recurrent scan. 256 blocks (one per batch), 8 waves (512 thr).
// Wave w owns h-columns [w*32, w*32+32) through ALL gates (z, r, hh).
// A-operand (hd / u) is broadcast to all 16 MFMA rows; every lane's
// acc[nt][0] holds col nt_base + r15, identical across the 4 lane-quads.
// Lane selection: quads 0-1 own col c0, quads 2-3 own c0+16.
// Schedule per step (R4):
//   phase A: read afr[8] from hd_bf, 16 r-MFMAs. epiA: u = pr*hd (5 ops),
//            ds_write u_bf. bar1.
//   phase B: 16 z-MFMAs from SAVED afr (zero-latency, covers u_bf ds_read
//            latency) -> 16 hh-MFMAs from u_bf. sigmoid(z) overlaps hh pipe.
//            epiB: tanh, h update, hd = g*hn, ds_write hd_bf. bar2.
// Only exposed gap left: bar2 -> phase A ds_read (~250-300 cyc).
// 2 lgkmcnt-only barriers/step. 48 weight frags pinned via asm.
// ---------------------------------------------------------------------------
__global__ __launch_bounds__(512, 2) void k_scan(
        const unsigned short* __restrict__ Apre, const unsigned short* __restrict__ G,
        const unsigned short* __restrict__ R_T, float* __restrict__ out) {
    int b = blockIdx.x;
    int tid = threadIdx.x, lane = tid & 63, w = tid >> 6;
    int r15 = lane & 15, q = lane >> 4;

    __shared__ __align__(16) unsigned short hd_bf[256];
    __shared__ __align__(16) unsigned short u_bf[256];
    __shared__ __align__(16) unsigned short ap_l[2][768];
    __shared__ __align__(16) unsigned short g_l[2][256];

    // ---- persistent weight fragments (192 regs/wave) ----
    // fZ[0..1]: z cols  w*32 + nt*16 + r15
    // fR[0..1]: r cols  256 + w*32 + nt*16 + r15
    // fH[0..1]: hh cols 512 + w*32 + nt*16 + r15
    bf16x8 fZ[2][8], fR[2][8], fH[2][8];
#pragma unroll
    for (int nt = 0; nt < 2; nt++) {
        const unsigned short* bz = R_T + (size_t)(w * 32 + nt * 16 + r15) * 256 + q * 8;
        const unsigned short* br = R_T + (size_t)(256 + w * 32 + nt * 16 + r15) * 256 + q * 8;
        const unsigned short* bh = R_T + (size_t)(512 + w * 32 + nt * 16 + r15) * 256 + q * 8;
#pragma unroll
        for (int kt = 0; kt < 8; kt++) {
            fZ[nt][kt] = ld_frag(bz + kt * 32);
            asm volatile("" : "+v"(fZ[nt][kt]));   // pin: no remat in loop
            fR[nt][kt] = ld_frag(br + kt * 32);
            asm volatile("" : "+v"(fR[nt][kt]));
            fH[nt][kt] = ld_frag(bh + kt * 32);
            asm volatile("" : "+v"(fH[nt][kt]));
        }
    }

    if (tid < 256) hd_bf[tid] = 0;

    const unsigned short* aprow = Apre + (size_t)b * Tsz * N3H;
    const unsigned short* grow  = G    + (size_t)b * Tsz * 256;

    // preload t=0 and t=1 rows (ap: 768 each, g: 256 each), uint2 = 4 ushorts
    if (tid < 192)      *(uint2*)&ap_l[0][tid * 4]         = *(const uint2*)(aprow + tid * 4);
    else if (tid < 384) *(uint2*)&ap_l[1][(tid-192) * 4]   = *(const uint2*)(aprow + N3H + (tid-192) * 4);
    else if (tid < 448) *(uint2*)&g_l[0][(tid-384) * 4]    = *(const uint2*)(grow + (tid-384) * 4);
    else                *(uint2*)&g_l[1][(tid-448) * 4]    = *(const uint2*)(grow + 256 + (tid-448) * 4);
    __syncthreads();

    // Lane's owned column: quads 0-1 -> c0, quads 2-3 -> c0+16.
    bool hiSel  = (q >= 2);
    bool writer = ((q & 1) == 0);            // q==0 or q==2: one writer per col
    int  col    = w * 32 + (hiSel ? 16 : 0) + r15;
    float h_reg  = 0.f;                      // h_{t-1}[col]
    float hd_reg = 0.f;                      // gamma_dh(t) * h_{t-1} [col]

    float* outb = out + (size_t)b * Tsz * 256;
    for (int t = 0; t < Tsz; t++) {
        int buf = t & 1;
        int tp2 = (t + 2 < Tsz) ? t + 2 : Tsz - 1;
        // prefetch row t+2 into a register (1 VGPR/thread)
        unsigned pf;
        if (tid < 384) pf = *(const unsigned*)(aprow + (size_t)tp2 * N3H + tid * 2);
        else           pf = *(const unsigned*)(grow  + (size_t)tp2 * 256 + (tid - 384) * 2);

        // hoisted scalar LDS read for epiA — latency hides under phase-A MFMAs
        unsigned short a_r = ap_l[buf][256 + col];

        // ---- phase A: r_pre = Apre[256:512] + hd @ R_r ----
        f32x4 accR[2];
        accR[0] = f32x4{0.f, 0.f, 0.f, 0.f};
        accR[1] = f32x4{0.f, 0.f, 0.f, 0.f};
        bf16x8 afr[8];                       // hd A-operand, SAVED across bar1
#pragma unroll
        for (int kt = 0; kt < 8; kt++) {
            afr[kt] = ld_frag(&hd_bf[kt * 32 + q * 8]);   // quad-uniform broadcast
            accR[0] = __builtin_amdgcn_mfma_f32_16x16x32_bf16(afr[kt], fR[0][kt], accR[0], 0, 0, 0);
            accR[1] = __builtin_amdgcn_mfma_f32_16x16x32_bf16(afr[kt], fR[1][kt], accR[1], 0, 0, 0);
        }
        // epilogue A: select own column, u = pre_r * hd (registers), publish.
        float pr = (hiSel ? accR[1][0] : accR[0][0]) + b2f(a_r);
        float u  = pr * hd_reg;
        if (writer) u_bf[col] = f2bf(u);
        barrier_lds();

        // ---- phase B: z-MFMAs from saved afr (ready at once), then hh ----
        unsigned short a_z = ap_l[buf][col];        // hoisted under phase-B pipe
        unsigned short a_h = ap_l[buf][512 + col];
        unsigned short g_v = g_l[buf ^ 1][col];
        f32x4 accZ[2], accH[2];
        accZ[0] = f32x4{0.f, 0.f, 0.f, 0.f};
        accZ[1] = f32x4{0.f, 0.f, 0.f, 0.f};
        accH[0] = f32x4{0.f, 0.f, 0.f, 0.f};
        accH[1] = f32x4{0.f, 0.f, 0.f, 0.f};
#pragma unroll
        for (int kt = 0; kt < 8; kt++) {
            accZ[0] = __builtin_amdgcn_mfma_f32_16x16x32_bf16(afr[kt], fZ[0][kt], accZ[0], 0, 0, 0);
            accZ[1] = __builtin_amdgcn_mfma_f32_16x16x32_bf16(afr[kt], fZ[1][kt], accZ[1], 0, 0, 0);
        }
#pragma unroll
        for (int kt = 0; kt < 8; kt++) {
            bf16x8 ufr = ld_frag(&u_bf[kt * 32 + q * 8]);
            accH[0] = __builtin_amdgcn_mfma_f32_16x16x32_bf16(ufr, fH[0][kt], accH[0], 0, 0, 0);
            accH[1] = __builtin_amdgcn_mfma_f32_16x16x32_bf16(ufr, fH[1][kt], accH[1], 0, 0, 0);
        }
        // sigmoid(z) overlaps the hh-MFMA window (accZ complete early in B)
        float pz = (hiSel ? accZ[1][0] : accZ[0][0]) + b2f(a_z);
        float z = 1.f / (1.f + __expf(-pz));
        // epilogue B: one column's chain per lane, all in registers
        float ph = (hiSel ? accH[1][0] : accH[0][0]) + b2f(a_h);
        float e2 = __expf(2.f * ph);
        float hh = 1.f - 2.f / (e2 + 1.f);          // tanh, inf-safe
        float hn = z * h_reg + (1.f - z) * hh;
        h_reg = hn;
        if (writer) outb[(size_t)t * 256 + col] = hn;
        hd_reg = b2f(g_v) * hn;                     // gamma_dh(t+1) * h_t
        if (writer) hd_bf[col] = f2bf(hd_reg);
        barrier_lds();

        // stash prefetched t+2 row into buf (t's data is dead now); the next
        // iteration's first barrier orders these writes before any consumer.
        if (tid < 384) *(unsigned*)&ap_l[buf][tid * 2] = pf;
        else           *(unsigned*)&g_l[buf][(tid - 384) * 2] = pf;
    }
}

// ---------------------------------------------------------------------------
extern "C" void kernel_launch(void* const* d_in, const int* in_sizes, int n_in,
                              void* d_out, int out_size, void* d_ws, size_t ws_size,
                              hipStream_t stream) {
    const float* x    = (const float*)d_in[0];
    const int*   m    = (const int*)  d_in[1];
    const float* s    = (const float*)d_in[2];
    const float* kern = (const float*)d_in[3];
    const float* rk   = (const float*)d_in[4];
    const float* mk   = (const float*)d_in[5];
    const float* bias = (const float*)d_in[6];
    const float* wdi  = (const float*)d_in[7];
    const float* bdi  = (const float*)d_in[8];
    const float* hdk  = (const float*)d_in[9];
    const float* hdb  = (const float*)d_in[10];
    float* out = (float*)d_out;

    char* ws = (char*)d_ws;
    size_t off = 0;
    auto alloc = [&](size_t bytes) -> void* {
        void* p = ws + off; off += (bytes + 255) & ~(size_t)255; return p;
    };
    unsigned short* X2   = (unsigned short*)alloc((size_t)BT * 256 * 2); // 67 MB
    unsigned short* Dt   = (unsigned short*)alloc((size_t)BT * 128 * 2); // 33.6 MB
    unsigned short* Apre = (unsigned short*)alloc((size_t)BT * N3H * 2); // 201 MB
    unsigned short* Gm   = (unsigned short*)alloc((size_t)BT * 256 * 2); // 67 MB
    unsigned short* KM_T = (unsigned short*)alloc((size_t)N3H * 256 * 2);
    unsigned short* R_T  = (unsigned short*)alloc((size_t)N3H * 256 * 2);
    unsigned short* W_T  = (unsigned short*)alloc((size_t)256 * 128 * 2);
    (void)ws_size; (void)in_sizes; (void)n_in; (void)out_size;

    k_pack<<<dim3((N3H * 256 + 256 * 128 + 255) / 256), dim3(256), 0, stream>>>(
        kern, mk, rk, hdk, KM_T, R_T, W_T);
    k_locf<<<dim3(Bsz * Dsz / 256), dim3(256), 0, stream>>>(x, m, s, wdi, bdi, X2, Dt);
    k_gemm<0, 256, N3H><<<dim3(BT / 128, N3H / 128), dim3(256), 0, stream>>>(X2, KM_T, bias, Apre);
    k_gemm<1, 128, 256><<<dim3(BT / 128, 256 / 128), dim3(256), 0, stream>>>(Dt, W_T, hdb, Gm);
    k_scan<<<dim3(Bsz), dim3(512), 0, stream>>>(Apre, Gm, R_T, out);
}

// Round 6
// 1070.722 us; speedup vs baseline: 1.0275x; 1.0275x over previous
//
#include <hip/hip_runtime.h>
#include <hip/hip_bf16.h>
#include <cstdint>

// ---------------------------------------------------------------------------
// GRU-D: B=256, T=512, D=128, H=256.
// R5: scan reverted to R3 (best measured, 696 us). k_gemm rewritten with
// global_load_lds width-16 staging (m97 recipe), 2-bit XOR chunk swizzle on
// both sides (pre-swizzled global source + swizzled frag read, linear LDS
// dest), and grid order (N/128, M/128) so blocks sharing an A panel are
// dispatch-adjacent (A fetched ~once instead of 6x).
// ---------------------------------------------------------------------------

#define Bsz 256
#define Tsz 512
#define Dsz 128
#define Hsz 256
#define BT  (Bsz * Tsz)          // 131072
#define N3H 768                  // 3*H

typedef __attribute__((ext_vector_type(8))) short   short8;
typedef __attribute__((ext_vector_type(8))) __bf16  bf16x8;
typedef __attribute__((ext_vector_type(4))) float   f32x4;

typedef const __attribute__((address_space(1))) unsigned char gas_t;
typedef __attribute__((address_space(3))) unsigned char las_t;

__device__ __forceinline__ unsigned short f2bf(float f) {
    union { float f; unsigned u; } v; v.f = f;
    unsigned r = v.u + 0x7fffu + ((v.u >> 16) & 1u);   // RNE
    return (unsigned short)(r >> 16);
}
__device__ __forceinline__ float b2f(unsigned short u) {
    union { unsigned u; float f; } v; v.u = ((unsigned)u) << 16;
    return v.f;
}
__device__ __forceinline__ bf16x8 ld_frag(const unsigned short* p) {
    short8 v = *(const short8*)p;
    return __builtin_bit_cast(bf16x8, v);
}

// LDS-only barrier: drains lgkmcnt but NOT vmcnt (scan only; all cross-wave
// traffic at scan sync points is through LDS).
__device__ __forceinline__ void barrier_lds() {
    asm volatile("s_waitcnt lgkmcnt(0)\n\ts_barrier" ::: "memory");
}

// ---------------------------------------------------------------------------
// K0: transpose+convert weights to bf16, N-major.
// ---------------------------------------------------------------------------
__global__ void k_pack(const float* __restrict__ kern, const float* __restrict__ maskk,
                       const float* __restrict__ rk,   const float* __restrict__ hdk,
                       unsigned short* __restrict__ KM_T, unsigned short* __restrict__ R_T,
                       unsigned short* __restrict__ W_T) {
    int i = blockIdx.x * 256 + threadIdx.x;
    if (i < N3H * 256) {
        int n = i >> 8, k = i & 255;
        float v = (k < 128) ? kern[k * N3H + n] : maskk[(k - 128) * N3H + n];
        KM_T[i] = f2bf(v);
        R_T[i]  = f2bf(rk[k * N3H + n]);
    } else {
        int j = i - N3H * 256;
        if (j < 256 * 128) {
            int n = j >> 7, k = j & 127;
            W_T[j] = f2bf(hdk[k * 256 + n]);
        }
    }
}

// ---------------------------------------------------------------------------
// K1: LOCF scan, one thread per (b,d).
// ---------------------------------------------------------------------------
__global__ __launch_bounds__(256) void k_locf(
        const float* __restrict__ x, const int* __restrict__ m,
        const float* __restrict__ s, const float* __restrict__ wdi,
        const float* __restrict__ bdi,
        unsigned short* __restrict__ X2, unsigned short* __restrict__ Dt) {
    int gid = blockIdx.x * blockDim.x + threadIdx.x;   // 32768
    int b = gid >> 7, d = gid & 127;
    float w  = wdi[d], bi = bdi[d];
    float x_keep = 0.f, s_prev = 0.f;
    const float* xb  = x + (size_t)b * Tsz * Dsz + d;
    const int*   mb_ = m + (size_t)b * Tsz * Dsz + d;
    const float* sb  = s + (size_t)b * Tsz;
    unsigned short* X2b = X2 + (size_t)b * Tsz * 256 + d;
    unsigned short* Dtb = Dt + (size_t)b * Tsz * 128 + d;
    for (int t0 = 0; t0 < Tsz; t0 += 4) {
        float xv[4], sv[4]; int mv[4];
#pragma unroll
        for (int u = 0; u < 4; u++) {
            xv[u] = xb[(size_t)(t0 + u) * Dsz];
            mv[u] = mb_[(size_t)(t0 + u) * Dsz];
            sv[u] = sb[t0 + u];
        }
#pragma unroll
        for (int u = 0; u < 4; u++) {
            int t = t0 + u;
            float dt  = sv[u] - s_prev;
            float gdi = __expf(-fmaxf(dt * w + bi, 0.f));
            bool  mbt = mv[u] > 0;
            if (mbt) x_keep = xv[u];
            float xe = mbt ? xv[u] : gdi * x_keep;
            if (mbt) s_prev = sv[u];
            X2b[(size_t)t * 256]       = f2bf(xe);
            X2b[(size_t)t * 256 + 128] = f2bf((float)mv[u]);
            Dtb[(size_t)t * 128]       = f2bf(dt);
        }
    }
}

// ---------------------------------------------------------------------------
// K2: bf16 MFMA GEMM, 128x128 tile, BK=32, 4 waves (2x2 of 64x64).
// global_load_lds (16B) staging, linear LDS [128][32] shorts, 2-bit XOR chunk
// swizzle: LDS (row, c) holds global (row, c ^ (row&3)); frag reads XOR back.
// grid: (N/128, M/128) — x-fastest => blocks sharing an A panel are adjacent.
// MODE 0: C = A@B + bias ; MODE 1: C = exp(-relu(A@B + bias)). C bf16.
// ---------------------------------------------------------------------------
template <int MODE, int K, int N>
__global__ __launch_bounds__(256) void k_gemm(
        const unsigned short* __restrict__ A, const unsigned short* __restrict__ Bt,
        const float* __restrict__ bias, unsigned short* __restrict__ C) {
    __shared__ unsigned short As[128 * 32];
    __shared__ unsigned short Bs[128 * 32];
    int n0 = blockIdx.x * 128, m0 = blockIdx.y * 128;
    int tid = threadIdx.x, lane = tid & 63, w = tid >> 6;
    int wm = w & 1, wn = w >> 1;
    int r15 = lane & 15, q = lane >> 4;

    // staging geometry: instruction j in {0,1} covers LDS bytes
    // [j*4096 + w*1024 + lane*16); row = j*64 + w*16 + (lane>>2), chunk = lane&3.
    int srow0 = w * 16 + (lane >> 2);        // j=0 row
    int chnkL = lane & 3;                    // LDS chunk this lane fills
    f32x4 acc[4][4];
#pragma unroll
    for (int i = 0; i < 4; i++)
#pragma unroll
        for (int j = 0; j < 4; j++) acc[i][j] = f32x4{0.f, 0.f, 0.f, 0.f};

    for (int kk = 0; kk < K; kk += 32) {
#pragma unroll
        for (int j = 0; j < 2; j++) {
            int row = srow0 + j * 64;
            int csrc = chnkL ^ (row & 3);    // pre-swizzled global source chunk
            const unsigned short* ga = A  + (size_t)(m0 + row) * K + kk + csrc * 8;
            const unsigned short* gb = Bt + (size_t)(n0 + row) * K + kk + csrc * 8;
            las_t* la = (las_t*)As + (size_t)(j * 4096 + w * 1024 + (lane & 63) * 16);
            las_t* lb = (las_t*)Bs + (size_t)(j * 4096 + w * 1024 + (lane & 63) * 16);
            __builtin_amdgcn_global_load_lds((gas_t*)ga, la, 16, 0, 0);
            __builtin_amdgcn_global_load_lds((gas_t*)gb, lb, 16, 0, 0);
        }
        __syncthreads();                     // drains vmcnt+lgkmcnt, then barrier
        bf16x8 af[4], bf[4];
#pragma unroll
        for (int i = 0; i < 4; i++) {
            int row = wm * 64 + i * 16 + r15;
            af[i] = ld_frag(&As[row * 32 + ((q ^ (row & 3)) << 3)]);
        }
#pragma unroll
        for (int j = 0; j < 4; j++) {
            int row = wn * 64 + j * 16 + r15;
            bf[j] = ld_frag(&Bs[row * 32 + ((q ^ (row & 3)) << 3)]);
        }
#pragma unroll
        for (int i = 0; i < 4; i++)
#pragma unroll
            for (int j = 0; j < 4; j++)
                acc[i][j] = __builtin_amdgcn_mfma_f32_16x16x32_bf16(af[i], bf[j], acc[i][j], 0, 0, 0);
        __syncthreads();
    }
#pragma unroll
    for (int i = 0; i < 4; i++)
#pragma unroll
        for (int j = 0; j < 4; j++) {
            int col = n0 + wn * 64 + j * 16 + r15;
            float bs = bias[col];
#pragma unroll
            for (int rg = 0; rg < 4; rg++) {
                int row = m0 + wm * 64 + i * 16 + q * 4 + rg;
                float v = acc[i][j][rg] + bs;
                if (MODE == 1) v = __expf(-fmaxf(v, 0.f));
                C[(size_t)row * N + col] = f2bf(v);
            }
        }
}

// ---------------------------------------------------------------------------
// K3: recurrent scan — R3 structure (best measured). 256 blocks, 8 waves.
// Wave w owns h-columns [w*32, w*32+32) through ALL gates (z, r, hh).
// A-operand is the hd / u vector broadcast to all 16 MFMA rows; every lane's
// acc[nt][0] holds col nt_base + r15, identical across the 4 lane-quads.
// Lane selection: quads 0-1 own col c0, quads 2-3 own c0+16; per-lane
// epilogue chain is a single column's worth of work.
// 2 lgkmcnt-only barriers/step. 48 weight frags (192 regs) pinned via asm.
// ---------------------------------------------------------------------------
__global__ __launch_bounds__(512, 2) void k_scan(
        const unsigned short* __restrict__ Apre, const unsigned short* __restrict__ G,
        const unsigned short* __restrict__ R_T, float* __restrict__ out) {
    int b = blockIdx.x;
    int tid = threadIdx.x, lane = tid & 63, w = tid >> 6;
    int r15 = lane & 15, q = lane >> 4;

    __shared__ __align__(16) unsigned short hd_bf[256];
    __shared__ __align__(16) unsigned short u_bf[256];
    __shared__ __align__(16) unsigned short ap_l[2][768];
    __shared__ __align__(16) unsigned short g_l[2][256];

    // ---- persistent weight fragments (192 regs/wave) ----
    // fzr[0..1]: z cols  w*32 + nt*16 + r15
    // fzr[2..3]: r cols  256 + w*32 + (nt-2)*16 + r15
    // fh [0..1]: hh cols 512 + w*32 + nt*16 + r15
    bf16x8 fzr[4][8];
    bf16x8 fh[2][8];
#pragma unroll
    for (int nt = 0; nt < 4; nt++) {
        int col = (nt < 2) ? (w * 32 + nt * 16 + r15)
                           : (256 + w * 32 + (nt - 2) * 16 + r15);
        const unsigned short* base = R_T + (size_t)col * 256 + q * 8;
#pragma unroll
        for (int kt = 0; kt < 8; kt++) {
            fzr[nt][kt] = ld_frag(base + kt * 32);
            asm volatile("" : "+v"(fzr[nt][kt]));   // pin: no remat in loop
        }
    }
#pragma unroll
    for (int nt = 0; nt < 2; nt++) {
        const unsigned short* base = R_T + (size_t)(512 + w * 32 + nt * 16 + r15) * 256 + q * 8;
#pragma unroll
        for (int kt = 0; kt < 8; kt++) {
            fh[nt][kt] = ld_frag(base + kt * 32);
            asm volatile("" : "+v"(fh[nt][kt]));
        }
    }

    if (tid < 256) hd_bf[tid] = 0;

    const unsigned short* aprow = Apre + (size_t)b * Tsz * N3H;
    const unsigned short* grow  = G    + (size_t)b * Tsz * 256;

    // preload t=0 and t=1 rows (ap: 768 each, g: 256 each), uint2 = 4 ushorts
    if (tid < 192)      *(uint2*)&ap_l[0][tid * 4]         = *(const uint2*)(aprow + tid * 4);
    else if (tid < 384) *(uint2*)&ap_l[1][(tid-192) * 4]   = *(const uint2*)(aprow + N3H + (tid-192) * 4);
    else if (tid < 448) *(uint2*)&g_l[0][(tid-384) * 4]    = *(const uint2*)(grow + (tid-384) * 4);
    else                *(uint2*)&g_l[1][(tid-448) * 4]    = *(const uint2*)(grow + 256 + (tid-448) * 4);
    __syncthreads();

    // Lane's owned column: quads 0-1 -> c0, quads 2-3 -> c0+16.
    bool hiSel  = (q >= 2);
    bool writer = ((q & 1) == 0);            // q==0 or q==2: one writer per col
    int  col    = w * 32 + (hiSel ? 16 : 0) + r15;
    float h_reg  = 0.f;                      // h_{t-1}[col]
    float hd_reg = 0.f;                      // gamma_dh(t) * h_{t-1} [col]

    float* outb = out + (size_t)b * Tsz * 256;
    for (int t = 0; t < Tsz; t++) {
        int buf = t & 1;
        int tp2 = (t + 2 < Tsz) ? t + 2 : Tsz - 1;
        // prefetch row t+2 into a register (1 VGPR/thread)
        unsigned pf;
        if (tid < 384) pf = *(const unsigned*)(aprow + (size_t)tp2 * N3H + tid * 2);
        else           pf = *(const unsigned*)(grow  + (size_t)tp2 * 256 + (tid - 384) * 2);

        // hoisted scalar LDS reads — latency hides under phase-A MFMAs
        unsigned short a_z = ap_l[buf][col];
        unsigned short a_r = ap_l[buf][256 + col];
        unsigned short a_h = ap_l[buf][512 + col];

        // ---- phase A: zr = Apre[:512] + h_d @ R_zr (wave-local columns) ----
        f32x4 acc[4];
#pragma unroll
        for (int nt = 0; nt < 4; nt++) acc[nt] = f32x4{0.f, 0.f, 0.f, 0.f};
#pragma unroll
        for (int kt = 0; kt < 8; kt++) {
            bf16x8 afr = ld_frag(&hd_bf[kt * 32 + q * 8]);   // quad-uniform broadcast
#pragma unroll
            for (int nt = 0; nt < 4; nt++)
                acc[nt] = __builtin_amdgcn_mfma_f32_16x16x32_bf16(afr, fzr[nt][kt], acc[nt], 0, 0, 0);
        }
        // epilogue A: select own column, u = pre_r * hd (registers), publish.
        float pz = (hiSel ? acc[1][0] : acc[0][0]) + b2f(a_z);
        float pr = (hiSel ? acc[3][0] : acc[2][0]) + b2f(a_r);
        float u  = pr * hd_reg;
        if (writer) u_bf[col] = f2bf(u);
        barrier_lds();

        // ---- phase B: hh = tanh(Apre[512:] + u @ Rh); h update ----
        unsigned short g_v = g_l[buf ^ 1][col];   // hoisted under phase-B MFMAs
        f32x4 acch[2];
        acch[0] = f32x4{0.f, 0.f, 0.f, 0.f};
        acch[1] = f32x4{0.f, 0.f, 0.f, 0.f};
#pragma unroll
        for (int kt = 0; kt < 8; kt++) {
            bf16x8 afr = ld_frag(&u_bf[kt * 32 + q * 8]);
            acch[0] = __builtin_amdgcn_mfma_f32_16x16x32_bf16(afr, fh[0][kt], acch[0], 0, 0, 0);
            acch[1] = __builtin_amdgcn_mfma_f32_16x16x32_bf16(afr, fh[1][kt], acch[1], 0, 0, 0);
        }
        // sigmoid of z overlaps the MFMA window (register-local, no ordering)
        float z = 1.f / (1.f + __expf(-pz));
        // epilogue B: one column's chain per lane, all in registers
        float ph = (hiSel ? acch[1][0] : acch[0][0]) + b2f(a_h);
        float e2 = __expf(2.f * ph);
        float hh = 1.f - 2.f / (e2 + 1.f);          // tanh, inf-safe
        float hn = z * h_reg + (1.f - z) * hh;
        h_reg = hn;
        if (writer) outb[(size_t)t * 256 + col] = hn;
        hd_reg = b2f(g_v) * hn;                     // gamma_dh(t+1) * h_t
        if (writer) hd_bf[col] = f2bf(hd_reg);
        barrier_lds();

        // stash prefetched t+2 row into buf (t's data is dead now); the next
        // iteration's first barrier orders these writes before any consumer.
        if (tid < 384) *(unsigned*)&ap_l[buf][tid * 2] = pf;
        else           *(unsigned*)&g_l[buf][(tid - 384) * 2] = pf;
    }
}

// ---------------------------------------------------------------------------
extern "C" void kernel_launch(void* const* d_in, const int* in_sizes, int n_in,
                              void* d_out, int out_size, void* d_ws, size_t ws_size,
                              hipStream_t stream) {
    const float* x    = (const float*)d_in[0];
    const int*   m    = (const int*)  d_in[1];
    const float* s    = (const float*)d_in[2];
    const float* kern = (const float*)d_in[3];
    const float* rk   = (const float*)d_in[4];
    const float* mk   = (const float*)d_in[5];
    const float* bias = (const float*)d_in[6];
    const float* wdi  = (const float*)d_in[7];
    const float* bdi  = (const float*)d_in[8];
    const float* hdk  = (const float*)d_in[9];
    const float* hdb  = (const float*)d_in[10];
    float* out = (float*)d_out;

    char* ws = (char*)d_ws;
    size_t off = 0;
    auto alloc = [&](size_t bytes) -> void* {
        void* p = ws + off; off += (bytes + 255) & ~(size_t)255; return p;
    };
    unsigned short* X2   = (unsigned short*)alloc((size_t)BT * 256 * 2); // 67 MB
    unsigned short* Dt   = (unsigned short*)alloc((size_t)BT * 128 * 2); // 33.6 MB
    unsigned short* Apre = (unsigned short*)alloc((size_t)BT * N3H * 2); // 201 MB
    unsigned short* Gm   = (unsigned short*)alloc((size_t)BT * 256 * 2); // 67 MB
    unsigned short* KM_T = (unsigned short*)alloc((size_t)N3H * 256 * 2);
    unsigned short* R_T  = (unsigned short*)alloc((size_t)N3H * 256 * 2);
    unsigned short* W_T  = (unsigned short*)alloc((size_t)256 * 128 * 2);
    (void)ws_size; (void)in_sizes; (void)n_in; (void)out_size;

    k_pack<<<dim3((N3H * 256 + 256 * 128 + 255) / 256), dim3(256), 0, stream>>>(
        kern, mk, rk, hdk, KM_T, R_T, W_T);
    k_locf<<<dim3(Bsz * Dsz / 256), dim3(256), 0, stream>>>(x, m, s, wdi, bdi, X2, Dt);
    // grid.x = N-blocks (fastest) so A-panel sharers are dispatch-adjacent
    k_gemm<0, 256, N3H><<<dim3(N3H / 128, BT / 128), dim3(256), 0, stream>>>(X2, KM_T, bias, Apre);
    k_gemm<1, 128, 256><<<dim3(256 / 128, BT / 128), dim3(256), 0, stream>>>(Dt, W_T, hdb, Gm);
    k_scan<<<dim3(Bsz), dim3(512), 0, stream>>>(Apre, Gm, R_T, out);
}